// Round 3
// baseline (99.347 us; speedup 1.0000x reference)
//
#include <hip/hip_runtime.h>
#include <math.h>

// ThermostatNN: B independent 40-step rollouts of a 2->64->1 MLP plant +
// hysteresis thermostat. One thread per batch element.
//
// R3 change vs R2:
//  - The compiler was REMATERIALIZING c[j] = aux*W1[1][j] + b1[j] inside the
//    t-loop every step (VGPR_Count=40 proves c[] was not resident), costing
//    ~6 VALU ops/hidden unit instead of 3 (the remat fma needs two SGPR
//    operands -> extra v_mov; plus the fma itself).
//    Fix: asm volatile("" : "+v"(c[j])) makes each c[j] an opaque VGPR value
//    the allocator cannot recompute -> it must keep all 64 live across the
//    t-loop. Budget is fine: __launch_bounds__(256,4) allows 128 VGPRs and
//    the grid only supplies 4 waves/SIMD anyway.
//  - Inner loop is then exactly: v_fma(temp, s_w1, c_j) + v_max(.,0) +
//    v_fma(h, s_w2, acc) = 3 VALU/hidden, each reading <=1 SGPR.
//
// NUMERICS (do not touch): serial single-accumulator dot in j order, expf-
// based stable sigmoid, explicitly rounded updates. R1/R2 measured absmax
// 0.0 (bit-identical to numpy). Reassociation risks flipping hysteresis
// comparisons (chaos amplification over 10.5M decisions).

#define LHID 64
#define NSTEPS 40

__global__ __launch_bounds__(256, 4) void thermostat_kernel(
    const float* __restrict__ x_init,  // (B,4): step, isOn, temp, aux
    const float* __restrict__ W1,      // (2,64) row-major
    const float* __restrict__ b1,      // (64)
    const float* __restrict__ W2,      // (64,1)
    const float* __restrict__ b2,      // (1)
    float* __restrict__ out,           // (40,B)
    int B)
{
    int b = blockIdx.x * blockDim.x + threadIdx.x;
    if (b >= B) return;

    float4 st = reinterpret_cast<const float4*>(x_init)[b];
    float step0 = st.x;
    float isOn  = st.y;
    float temp  = st.z;
    float aux   = st.w;
    float bias2 = b2[0];

    // number of active iterations (step0 == 0 in practice)
    int n_active = (int)fminf(fmaxf((float)NSTEPS - step0, 0.0f), (float)NSTEPS);

    // Per-thread invariant part of layer 1: c[j] = aux*W1[1][j] + b1[j].
    // The empty asm pins each value in a VGPR: the allocator can no longer
    // rematerialize it inside the t-loop.
    float c[LHID];
#pragma unroll
    for (int j = 0; j < LHID; ++j) {
        c[j] = fmaf(aux, W1[LHID + j], b1[j]);
        asm volatile("" : "+v"(c[j]));
    }

#pragma unroll 1
    for (int t = 0; t < NSTEPS; ++t) {
        // ---- plant NN: s = sigmoid(relu([temp,aux]@W1 + b1) @ W2 + b2) ----
        float acc = 0.0f;
#pragma unroll
        for (int j = 0; j < LHID; ++j) {
            float h = fmaf(temp, W1[j], c[j]);   // v_fma: v,s,v
            h = fmaxf(h, 0.0f);                  // v_max with inline 0
            acc = fmaf(h, W2[j], acc);           // v_fma: v,s,v (serial; order matters)
        }
        float x = __fadd_rn(acc, bias2);

        // numerically stable sigmoid (matches numpy ref; absmax == 0.0)
        float e = expf(-fabsf(x));
        float s;
        if (x >= 0.0f) s = 1.0f / (1.0f + e);
        else           s = e / (1.0f + e);

        // plant = s*10 - 5 ; dtemp = plant*10
        float plant = __fsub_rn(__fmul_rn(s, 10.0f), 5.0f);
        float dtemp = __fmul_rn(plant, 10.0f);

        float tn_off = __fadd_rn(temp, dtemp);
        float tn_on  = __fadd_rn(tn_off, 5.0f);

        bool off = (isOn <= 0.5f);
        float temp_new = off ? tn_off : tn_on;
        float isOn_new;
        if (off) isOn_new = (temp_new <= 66.0f) ? 1.0f : isOn;
        else     isOn_new = (temp_new <= 78.0f) ? isOn : 0.0f;

        if (t < n_active) {
            temp = temp_new;
            isOn = isOn_new;
        }

        out[(size_t)t * B + b] = temp;
    }
}

extern "C" void kernel_launch(void* const* d_in, const int* in_sizes, int n_in,
                              void* d_out, int out_size, void* d_ws, size_t ws_size,
                              hipStream_t stream) {
    const float* x_init = (const float*)d_in[0];
    const float* W1     = (const float*)d_in[1];
    const float* b1     = (const float*)d_in[2];
    const float* W2     = (const float*)d_in[3];
    const float* b2     = (const float*)d_in[4];
    float* out = (float*)d_out;

    int B = in_sizes[0] / 4;
    int threads = 256;
    int blocks = (B + threads - 1) / threads;
    thermostat_kernel<<<blocks, threads, 0, stream>>>(x_init, W1, b1, W2, b2, out, B);
}

// Round 4
// 58.817 us; speedup vs baseline: 1.6891x; 1.6891x over previous
//
#include <hip/hip_runtime.h>
#include <math.h>

// ThermostatNN: B independent 40-step rollouts of a 2->64->1 MLP plant +
// hysteresis thermostat. One thread per batch element.
//
// R4 change vs R3 (theory: SGPR-file overflow forced per-step weight
// streaming + c-remat => ~600 VALU insts/step instead of ~215):
//  - ALL step-invariant operands now live in per-lane VGPRs:
//      a[j]  = W1[0][j]                (uniform, broadcast-loaded)
//      w2[j] = W2[j]                   (uniform, broadcast-loaded)
//      c[j]  = aux*W1[1][j] + b1[j]    (per-thread)
//    each pinned with asm volatile so the allocator can neither remat nor
//    re-stream them. The 128 uniform floats CANNOT fit in the ~102-SGPR
//    file, which is why every SGPR-based variant degenerated.
//  - __launch_bounds__(256, 1): VGPR budget 512; expected use ~210 ->
//    2 waves/SIMD. Issue demand per wave-step (~430 cyc) >> acc-chain
//    latency (256 cyc), so 2 resident waves keep the SIMD issue port full.
//  - Inner loop: 64 x { v_fma(v,v,v); v_max(v,0); v_fma(v,v,v) } -- no SGPR
//    reads, no s_loads, no waitcnts in steady state.
//
// NUMERICS (do not touch): serial single-accumulator dot in j order, expf-
// based stable sigmoid, explicitly rounded updates. Measured absmax == 0.0
// vs numpy in R1-R3; op order and rounding must stay bit-identical.

#define LHID 64
#define NSTEPS 40

__global__ __launch_bounds__(256, 1) void thermostat_kernel(
    const float* __restrict__ x_init,  // (B,4): step, isOn, temp, aux
    const float* __restrict__ W1,      // (2,64) row-major
    const float* __restrict__ b1,      // (64)
    const float* __restrict__ W2,      // (64,1)
    const float* __restrict__ b2,      // (1)
    float* __restrict__ out,           // (40,B)
    int B)
{
    int b = blockIdx.x * blockDim.x + threadIdx.x;
    if (b >= B) return;

    float4 st = reinterpret_cast<const float4*>(x_init)[b];
    float step0 = st.x;
    float isOn  = st.y;
    float temp  = st.z;
    float aux   = st.w;
    float bias2 = b2[0];

    // number of active iterations (step0 == 0 in practice)
    int n_active = (int)fminf(fmaxf((float)NSTEPS - step0, 0.0f), (float)NSTEPS);

    // Step-invariant operands -> per-lane VGPRs, pinned opaque.
    float a[LHID];   // W1 row 0
    float w2[LHID];  // W2
    float c[LHID];   // aux*W1row1 + b1 (per-thread)
#pragma unroll
    for (int j = 0; j < LHID; j += 4) {
        float4 va  = *reinterpret_cast<const float4*>(&W1[j]);          // row 0
        float4 vr1 = *reinterpret_cast<const float4*>(&W1[LHID + j]);   // row 1
        float4 vb  = *reinterpret_cast<const float4*>(&b1[j]);
        float4 vw2 = *reinterpret_cast<const float4*>(&W2[j]);
        a[j+0] = va.x;  a[j+1] = va.y;  a[j+2] = va.z;  a[j+3] = va.w;
        w2[j+0] = vw2.x; w2[j+1] = vw2.y; w2[j+2] = vw2.z; w2[j+3] = vw2.w;
        c[j+0] = fmaf(aux, vr1.x, vb.x);
        c[j+1] = fmaf(aux, vr1.y, vb.y);
        c[j+2] = fmaf(aux, vr1.z, vb.z);
        c[j+3] = fmaf(aux, vr1.w, vb.w);
    }
#pragma unroll
    for (int j = 0; j < LHID; ++j) {
        asm volatile("" : "+v"(a[j]));
        asm volatile("" : "+v"(w2[j]));
        asm volatile("" : "+v"(c[j]));
    }

#pragma unroll 1
    for (int t = 0; t < NSTEPS; ++t) {
        // ---- plant NN: s = sigmoid(relu([temp,aux]@W1 + b1) @ W2 + b2) ----
        float acc = 0.0f;
#pragma unroll
        for (int j = 0; j < LHID; ++j) {
            float h = fmaf(temp, a[j], c[j]);    // v_fma, all-VGPR
            h = fmaxf(h, 0.0f);                  // v_max with inline 0
            acc = fmaf(h, w2[j], acc);           // v_fma, all-VGPR (serial; order matters)
        }
        float x = __fadd_rn(acc, bias2);

        // numerically stable sigmoid (matches numpy ref; absmax == 0.0)
        float e = expf(-fabsf(x));
        float s;
        if (x >= 0.0f) s = 1.0f / (1.0f + e);
        else           s = e / (1.0f + e);

        // plant = s*10 - 5 ; dtemp = plant*10
        float plant = __fsub_rn(__fmul_rn(s, 10.0f), 5.0f);
        float dtemp = __fmul_rn(plant, 10.0f);

        float tn_off = __fadd_rn(temp, dtemp);
        float tn_on  = __fadd_rn(tn_off, 5.0f);

        bool off = (isOn <= 0.5f);
        float temp_new = off ? tn_off : tn_on;
        float isOn_new;
        if (off) isOn_new = (temp_new <= 66.0f) ? 1.0f : isOn;
        else     isOn_new = (temp_new <= 78.0f) ? isOn : 0.0f;

        if (t < n_active) {
            temp = temp_new;
            isOn = isOn_new;
        }

        out[(size_t)t * B + b] = temp;
    }
}

extern "C" void kernel_launch(void* const* d_in, const int* in_sizes, int n_in,
                              void* d_out, int out_size, void* d_ws, size_t ws_size,
                              hipStream_t stream) {
    const float* x_init = (const float*)d_in[0];
    const float* W1     = (const float*)d_in[1];
    const float* b1     = (const float*)d_in[2];
    const float* W2     = (const float*)d_in[3];
    const float* b2     = (const float*)d_in[4];
    float* out = (float*)d_out;

    int B = in_sizes[0] / 4;
    int threads = 256;
    int blocks = (B + threads - 1) / threads;
    thermostat_kernel<<<blocks, threads, 0, stream>>>(x_init, W1, b1, W2, b2, out, B);
}

// Round 5
// 55.509 us; speedup vs baseline: 1.7897x; 1.0596x over previous
//
#include <hip/hip_runtime.h>
#include <math.h>

// ThermostatNN: B independent 40-step rollouts of a 2->64->1 MLP plant +
// hysteresis thermostat. One thread per batch element.
//
// R5 change vs R4 (theory: AGPR round-trips doubled VALU count):
//  R4 pinned 192 uniform floats in "VGPRs" but VGPR_Count=104 showed the
//  allocator parked them in AGPRs, emitting v_accvgpr_read before every use:
//  +192 VALU/step (measured ~440 insts/step vs ~220 source-level).
//  Fix: uniform weights (W1 row 0, W2) now live in LDS (512 B), read per
//  step as float4 -> ds_read_b128 broadcast (all lanes same addr, conflict-
//  free). ds_read issues on the LDS pipe and overlaps VALU issue from other
//  waves, so those 32 insts/step are ~free. Only the per-lane c[64] stays
//  pinned in arch VGPRs (~104 total -> 4 waves/SIMD, no AGPR pressure).
//  Also: single-division sigmoid (select numerator, one exact div -- values
//  bitwise identical to the two-branch form), incremental output pointer.
//
// NUMERICS (do not touch): serial single-accumulator dot in j order, expf-
// based stable sigmoid, explicitly rounded updates. absmax == 0.0 in R1-R4;
// op order and rounding must stay bit-identical. No reassociation: a ~1e-7
// perturbation can flip hysteresis decisions (10.5M of them) and a single
// flip diverges the trajectory by O(100).

#define LHID 64
#define NSTEPS 40

__global__ __launch_bounds__(256, 2) void thermostat_kernel(
    const float* __restrict__ x_init,  // (B,4): step, isOn, temp, aux
    const float* __restrict__ W1,      // (2,64) row-major
    const float* __restrict__ b1,      // (64)
    const float* __restrict__ W2,      // (64,1)
    const float* __restrict__ b2,      // (1)
    float* __restrict__ out,           // (40,B)
    int B)
{
    __shared__ __align__(16) float lds_a[LHID];   // W1 row 0
    __shared__ __align__(16) float lds_w2[LHID];  // W2

    int tid = threadIdx.x;
    if (tid < LHID) {
        lds_a[tid]  = W1[tid];
        lds_w2[tid] = W2[tid];
    }
    __syncthreads();

    int b = blockIdx.x * blockDim.x + tid;
    if (b >= B) return;

    float4 st = reinterpret_cast<const float4*>(x_init)[b];
    float step0 = st.x;
    float isOn  = st.y;
    float temp  = st.z;
    float aux   = st.w;
    float bias2 = b2[0];

    // number of active iterations: #t with step0 + t < NSTEPS
    int n_active = (int)ceilf(fminf(fmaxf((float)NSTEPS - step0, 0.0f), (float)NSTEPS));

    // Per-thread invariant part of layer 1: c[j] = aux*W1[1][j] + b1[j].
    // Pinned opaque so the allocator cannot rematerialize (R2/R3 lesson).
    float c[LHID];
#pragma unroll
    for (int j = 0; j < LHID; j += 4) {
        float4 vr1 = *reinterpret_cast<const float4*>(&W1[LHID + j]);
        float4 vb  = *reinterpret_cast<const float4*>(&b1[j]);
        c[j+0] = fmaf(aux, vr1.x, vb.x);
        c[j+1] = fmaf(aux, vr1.y, vb.y);
        c[j+2] = fmaf(aux, vr1.z, vb.z);
        c[j+3] = fmaf(aux, vr1.w, vb.w);
    }
#pragma unroll
    for (int j = 0; j < LHID; ++j) {
        asm volatile("" : "+v"(c[j]));
    }

    float* po = out + b;

#pragma unroll 1
    for (int t = 0; t < NSTEPS; ++t) {
        // ---- plant NN: s = sigmoid(relu([temp,aux]@W1 + b1) @ W2 + b2) ----
        float acc = 0.0f;
#pragma unroll
        for (int j = 0; j < LHID; j += 4) {
            float4 av = *reinterpret_cast<const float4*>(&lds_a[j]);   // ds_read_b128
            float4 wv = *reinterpret_cast<const float4*>(&lds_w2[j]);  // ds_read_b128
            float h0 = fmaxf(fmaf(temp, av.x, c[j+0]), 0.0f); acc = fmaf(h0, wv.x, acc);
            float h1 = fmaxf(fmaf(temp, av.y, c[j+1]), 0.0f); acc = fmaf(h1, wv.y, acc);
            float h2 = fmaxf(fmaf(temp, av.z, c[j+2]), 0.0f); acc = fmaf(h2, wv.z, acc);
            float h3 = fmaxf(fmaf(temp, av.w, c[j+3]), 0.0f); acc = fmaf(h3, wv.w, acc);
        }
        float x = __fadd_rn(acc, bias2);

        // stable sigmoid, single exact division (bitwise == two-branch form)
        float e = expf(-fabsf(x));
        float num = (x >= 0.0f) ? 1.0f : e;
        float s = num / (1.0f + e);

        // plant = s*10 - 5 ; dtemp = plant*10
        float plant = __fsub_rn(__fmul_rn(s, 10.0f), 5.0f);
        float dtemp = __fmul_rn(plant, 10.0f);

        float tn_off = __fadd_rn(temp, dtemp);
        float tn_on  = __fadd_rn(tn_off, 5.0f);

        bool off = (isOn <= 0.5f);
        float temp_new = off ? tn_off : tn_on;
        float isOn_new;
        if (off) isOn_new = (temp_new <= 66.0f) ? 1.0f : isOn;
        else     isOn_new = (temp_new <= 78.0f) ? isOn : 0.0f;

        if (t < n_active) {
            temp = temp_new;
            isOn = isOn_new;
        }

        *po = temp;
        po += B;
    }
}

extern "C" void kernel_launch(void* const* d_in, const int* in_sizes, int n_in,
                              void* d_out, int out_size, void* d_ws, size_t ws_size,
                              hipStream_t stream) {
    const float* x_init = (const float*)d_in[0];
    const float* W1     = (const float*)d_in[1];
    const float* b1     = (const float*)d_in[2];
    const float* W2     = (const float*)d_in[3];
    const float* b2     = (const float*)d_in[4];
    float* out = (float*)d_out;

    int B = in_sizes[0] / 4;
    int threads = 256;
    int blocks = (B + threads - 1) / threads;
    thermostat_kernel<<<blocks, threads, 0, stream>>>(x_init, W1, b1, W2, b2, out, B);
}